// Round 12
// baseline (179.292 us; speedup 1.0000x reference)
//
#include <hip/hip_runtime.h>
#include <hip/hip_bf16.h>
#include <hip/hip_fp16.h>
#include <math.h>

typedef _Float16 f16;
typedef _Float16 f16x8 __attribute__((ext_vector_type(8)));
typedef _Float16 f16x4 __attribute__((ext_vector_type(4)));
typedef _Float16 f16x2 __attribute__((ext_vector_type(2)));
typedef unsigned short u16x8v __attribute__((ext_vector_type(8)));
typedef float f32x4 __attribute__((ext_vector_type(4)));

namespace {
constexpr int B = 2;
constexpr int H = 16;
constexpr int S = 2048;
constexpr int D = 64;
constexpr int E = 1024;
// fold 1/sqrt(64) * log2(e) into Q so softmax uses exp2 directly
constexpr float QSCALE = 0.125f * 1.4426950408889634f;
}

#define GLOBAL_LOAD_LDS16(gp, lp)                                              \
  __builtin_amdgcn_global_load_lds(                                            \
      (const __attribute__((address_space(1))) void*)(gp),                     \
      (__attribute__((address_space(3))) void*)(lp), 16, 0, 0)

// ---------- prep (tiny): Wkv = Wk*Wv, bkv = Wk*bv + bk
__global__ __launch_bounds__(256) void prep(const float* __restrict__ Wk, const float* __restrict__ Wv,
                                            const float* __restrict__ bv, const float* __restrict__ bk,
                                            float* __restrict__ Wkv, float* __restrict__ bkv) {
  const int g = blockIdx.x * 256 + threadIdx.x;   // 0..4095
  const int i = g >> 6, j = g & 63;
  float s = 0.f;
#pragma unroll 16
  for (int d = 0; d < 64; ++d) s = fmaf(Wk[i * 64 + d], Wv[d * 64 + j], s);
  Wkv[g] = s;
  if (g < 64) {
    float bb = bk[g];
#pragma unroll 16
    for (int d = 0; d < 64; ++d) bb = fmaf(Wk[g * 64 + d], bv[d], bb);
    bkv[g] = bb;
  }
}

// ---------- ALL projections + Wd cvt in ONE launch (concurrency for the small
// memory-bound passes; was 3 serial under-occupied launches).
// blocks [0,1024): Wd fp32->f16.   [1024,1280): Q-proj (natural [b][s][h][d]).
// [1280,1536): K-proj (LDS bounce, [b][h][s][d]).   [1536,2560): V-proj
// (transposed+permuted vtp[b][h][d][S]).
__global__ __launch_bounds__(256) void proj_all(const float* __restrict__ xq,
                                                const float* __restrict__ xv,
                                                const float* __restrict__ Wq,
                                                const float* __restrict__ bq,
                                                const float* __restrict__ Wkv,
                                                const float* __restrict__ bkv,
                                                const float* __restrict__ Wv,
                                                const float* __restrict__ bv,
                                                const float* __restrict__ Wd,
                                                f16* __restrict__ qp,
                                                f16* __restrict__ kp,
                                                f16* __restrict__ vtp,
                                                f16* __restrict__ wd16) {
  __shared__ f16 tb[16 * 16 * 68];   // K bounce [h*16+sl][68]; V bounce [d][72] (subset)
  const int bid = blockIdx.x;
  const int t = threadIdx.x;

  if (bid < 1024) {   // ---- Wd fp32 -> f16
    const int i = bid * 256 + t;
    const float4 f = ((const float4*)Wd)[i];
    f16x4 o;
    o.x = (f16)f.x; o.y = (f16)f.y; o.z = (f16)f.z; o.w = (f16)f.w;
    *(f16x4*)(wd16 + 4 * (size_t)i) = o;
    return;
  }

  const int lane = t & 63, w = t >> 6;
  const int l15 = lane & 15, quad = lane >> 4;

  if (bid < 1536) {   // ---- Q (which=0) or K (which=1) projection
    const int which = (bid >= 1280) ? 1 : 0;
    const int bx = bid - (which ? 1280 : 1024);
    const float* x    = which ? xv : xq;
    const float* W    = which ? Wkv : Wq;
    const float* bias = which ? bkv : bq;
    const float scale = which ? 1.0f : QSCALE;
    const int m0 = (bx * 4 + w) * 64;

    f16x8 af[4][2];
#pragma unroll
    for (int mt = 0; mt < 4; ++mt)
#pragma unroll
      for (int kc = 0; kc < 2; ++kc) {
        const float* g = x + (size_t)(m0 + mt * 16 + l15) * 64 + kc * 32 + quad * 8;
        const float4 a = *(const float4*)g, b2 = *(const float4*)(g + 4);
        f16x8 v;
        v[0]=(f16)a.x; v[1]=(f16)a.y; v[2]=(f16)a.z; v[3]=(f16)a.w;
        v[4]=(f16)b2.x; v[5]=(f16)b2.y; v[6]=(f16)b2.z; v[7]=(f16)b2.w;
        af[mt][kc] = v;
      }

    f16x8 wf[4][2];
#pragma unroll
    for (int nt = 0; nt < 4; ++nt)
#pragma unroll
      for (int kc = 0; kc < 2; ++kc) {
        const float* g = W + (size_t)(nt * 16 + l15) * 64 + kc * 32 + quad * 8;
        const float4 a = *(const float4*)g, b2 = *(const float4*)(g + 4);
        f16x8 v;
        v[0]=(f16)a.x; v[1]=(f16)a.y; v[2]=(f16)a.z; v[3]=(f16)a.w;
        v[4]=(f16)b2.x; v[5]=(f16)b2.y; v[6]=(f16)b2.z; v[7]=(f16)b2.w;
        wf[nt][kc] = v;
      }

    f32x4 acc[4][4];   // [nt][mt]: rows m = mt*16+l15, cols n = nt*16+quad*4+r
#pragma unroll
    for (int nt = 0; nt < 4; ++nt)
#pragma unroll
      for (int mt = 0; mt < 4; ++mt) acc[nt][mt] = (f32x4){0.f, 0.f, 0.f, 0.f};
#pragma unroll
    for (int kc = 0; kc < 2; ++kc)
#pragma unroll
      for (int nt = 0; nt < 4; ++nt)
#pragma unroll
        for (int mt = 0; mt < 4; ++mt)
          acc[nt][mt] = __builtin_amdgcn_mfma_f32_16x16x32_f16(wf[nt][kc], af[mt][kc], acc[nt][mt], 0, 0, 0);

    float4 bl4[4];
#pragma unroll
    for (int nt = 0; nt < 4; ++nt) bl4[nt] = *(const float4*)&bias[nt * 16 + quad * 4];

#pragma unroll
    for (int mt = 0; mt < 4; ++mt) {
      const int g = m0 + mt * 16 + l15;   // (b*S+s)*H + h
#pragma unroll
      for (int nt = 0; nt < 4; ++nt) {
        const float p0 = (acc[nt][mt][0] + bl4[nt].x) * scale;
        const float p1 = (acc[nt][mt][1] + bl4[nt].y) * scale;
        const float p2 = (acc[nt][mt][2] + bl4[nt].z) * scale;
        const float p3 = (acc[nt][mt][3] + bl4[nt].w) * scale;
        union { f16x4 v4; f16x2 hh[2]; } u;
        u.hh[0] = __builtin_bit_cast(f16x2, __builtin_amdgcn_cvt_pkrtz(p0, p1));
        u.hh[1] = __builtin_bit_cast(f16x2, __builtin_amdgcn_cvt_pkrtz(p2, p3));
        if (which) {
          *(f16x4*)&tb[(l15 * 16 + w * 4 + mt) * 68 + nt * 16 + quad * 4] = u.v4;
        } else {
          *(f16x4*)(qp + (size_t)g * 64 + nt * 16 + quad * 4) = u.v4;   // [b][s][h][d]
        }
      }
    }

    if (which) {
      __syncthreads();
      const int bsb = bx * 16;
      const int bb = bsb >> 11;
      const int sblk = bsb & 2047;
      const int h = t >> 4, sl = t & 15;
      f16* dst = kp + ((size_t)(bb * H + h) * S + sblk + sl) * 64;
      const f16* src = &tb[t * 68];
#pragma unroll
      for (int c = 0; c < 8; ++c)
        *(f16x8*)(dst + c * 8) = *(const f16x8*)(src + c * 8);
    }
    return;
  }

  // ---- V projection: block = (one h, 64 s, 64 d); vtp[b][h][d][S] with kv-perm
  // perm (attn reads kv(p) = (p>>5)*32 + ((p&7)>>2)*16 + ((p>>3)&3)*4 + (p&3)):
  // inverse: p = kv5*32 + kv3*16 + kv2*8 + kv4*4 + (kv&3).
  {
    const int v = bid - 1536;               // 0..1023
    const int bx = v & 63, h = v >> 6;
    const int b = bx >> 5, s0 = (bx & 31) * 64;

    f16x8 af[2];
#pragma unroll
    for (int kc = 0; kc < 2; ++kc) {
      const float* g = xv + ((size_t)(b * S + s0 + w * 16 + l15) * H + h) * 64 + kc * 32 + quad * 8;
      const float4 a = *(const float4*)g, b2 = *(const float4*)(g + 4);
      f16x8 vv;
      vv[0]=(f16)a.x; vv[1]=(f16)a.y; vv[2]=(f16)a.z; vv[3]=(f16)a.w;
      vv[4]=(f16)b2.x; vv[5]=(f16)b2.y; vv[6]=(f16)b2.z; vv[7]=(f16)b2.w;
      af[kc] = vv;
    }
    f16x8 wf[4][2];
#pragma unroll
    for (int nt = 0; nt < 4; ++nt)
#pragma unroll
      for (int kc = 0; kc < 2; ++kc) {
        const float* g = Wv + (size_t)(nt * 16 + l15) * 64 + kc * 32 + quad * 8;
        const float4 a = *(const float4*)g, b2 = *(const float4*)(g + 4);
        f16x8 vv;
        vv[0]=(f16)a.x; vv[1]=(f16)a.y; vv[2]=(f16)a.z; vv[3]=(f16)a.w;
        vv[4]=(f16)b2.x; vv[5]=(f16)b2.y; vv[6]=(f16)b2.z; vv[7]=(f16)b2.w;
        wf[nt][kc] = vv;
      }

    f32x4 acc[4];   // [nt]: C[s][d], col d = nt*16+l15, rows s = w*16 + quad*4 + r
#pragma unroll
    for (int nt = 0; nt < 4; ++nt) acc[nt] = (f32x4){0.f, 0.f, 0.f, 0.f};
#pragma unroll
    for (int kc = 0; kc < 2; ++kc)
#pragma unroll
      for (int nt = 0; nt < 4; ++nt)
        acc[nt] = __builtin_amdgcn_mfma_f32_16x16x32_f16(af[kc], wf[nt][kc], acc[nt], 0, 0, 0);

    float bl[4];
#pragma unroll
    for (int nt = 0; nt < 4; ++nt) bl[nt] = bv[nt * 16 + l15];

#pragma unroll
    for (int nt = 0; nt < 4; ++nt)
#pragma unroll
      for (int r = 0; r < 4; ++r)
        tb[(nt * 16 + l15) * 72 + w * 16 + quad * 4 + r] = (f16)(acc[nt][r] + bl[nt]);

    __syncthreads();
    const int d = t >> 2;
    f16* orow = vtp + ((size_t)(b * H + h) * 64 + d) * S + s0;
    const f16* src = &tb[d * 72];
#pragma unroll
    for (int j = 0; j < 4; ++j) {
      const int g = (t & 3) * 4 + j;   // g = kv>>2
      const int p = ((g >> 3) & 1) * 32 + ((g >> 1) & 1) * 16 + (g & 1) * 8 + ((g >> 2) & 1) * 4;
      *(f16x4*)(orow + p) = *(const f16x4*)(src + g * 4);
    }
  }
}

// ---------- MFMA flash attention v10 (unchanged from round 11): KV-split across waves,
// 4 blocks/CU, depth-2 gload_lds, in-register P, XOR chunk swizzle, LDS O-reduce.
__global__ __launch_bounds__(256, 4) void attn_mfma(const f16* __restrict__ qp,
                                                    const f16* __restrict__ kp,
                                                    const f16* __restrict__ vtp,
                                                    f16* __restrict__ ao) {
  __shared__ f16 smem[4][64 * 64];   // [0,1]=K dbuf, [2,3]=V dbuf; f32 scratch at epilogue
  const int t = threadIdx.x, lane = t & 63, w = t >> 6;
  const int l15 = lane & 15, quad = lane >> 4;
  const int wq = w >> 1, wk = w & 1;
  const int bh = blockIdx.x;
  const int b = bh >> 4, h = bh & 15;
  const int q0 = blockIdx.y * 64;
  const f16* kbase = kp + (size_t)bh * S * D;
  const f16* vtbase = vtp + (size_t)bh * 64 * S;

  const int row1 = t >> 3;
  const size_t koff1 = (size_t)row1 * D + (((t & 7) ^ (row1 & 7)) * 8);
  const size_t koff2 = koff1 + (size_t)32 * D;
  const size_t voff1 = (size_t)row1 * S + (((t & 7) ^ (row1 & 7)) * 8);
  const size_t voff2 = voff1 + (size_t)32 * S;

  f16x8 qf[2][2];
#pragma unroll
  for (int mt = 0; mt < 2; ++mt)
#pragma unroll
    for (int kc = 0; kc < 2; ++kc)
      qf[mt][kc] = *(const f16x8*)(qp +
          ((size_t)(b * S + q0 + wq * 32 + mt * 16 + l15) * H + h) * 64 + kc * 32 + quad * 8);

  f16x8 vb4;
#pragma unroll
  for (int j = 0; j < 8; ++j) vb4[j] = (l15 == 0) ? (f16)1.0f : (f16)0.0f;

  f32x4 O[2][5];
#pragma unroll
  for (int mt = 0; mt < 2; ++mt)
#pragma unroll
    for (int nt = 0; nt < 5; ++nt) O[mt][nt] = (f32x4){0.f, 0.f, 0.f, 0.f};

#define ISSUE_TILE(tt, buf)                                                    \
  {                                                                            \
    const f16* gk = kbase + (size_t)(tt) * (64 * D);                           \
    GLOBAL_LOAD_LDS16(gk + koff1, &smem[buf][t * 8]);                          \
    GLOBAL_LOAD_LDS16(gk + koff2, &smem[buf][(t + 256) * 8]);                  \
    const f16* gv = vtbase + (size_t)(tt) * 64;                                \
    GLOBAL_LOAD_LDS16(gv + voff1, &smem[2 + (buf)][t * 8]);                    \
    GLOBAL_LOAD_LDS16(gv + voff2, &smem[2 + (buf)][(t + 256) * 8]);            \
  }

  ISSUE_TILE(0, 0);

  for (int kt = 0; kt < S / 64; ++kt) {
    const int rb = kt & 1;
    __asm__ volatile("s_waitcnt vmcnt(0)" ::: "memory");
    __builtin_amdgcn_s_barrier();
    __asm__ volatile("" ::: "memory");
    if (kt + 1 < S / 64) ISSUE_TILE(kt + 1, rb ^ 1);

    f32x4 sc[2][2];   // [ntl][mt]
#pragma unroll
    for (int ntl = 0; ntl < 2; ++ntl)
#pragma unroll
      for (int mt = 0; mt < 2; ++mt) sc[ntl][mt] = (f32x4){0.f, 0.f, 0.f, 0.f};
    __builtin_amdgcn_s_setprio(1);
#pragma unroll
    for (int kcq = 0; kcq < 2; ++kcq)
#pragma unroll
      for (int ntl = 0; ntl < 2; ++ntl) {
        const f16x8 kf = *(const f16x8*)&smem[rb][(wk * 32 + ntl * 16 + l15) * 64 + (((kcq * 4 + quad) ^ (l15 & 7)) * 8)];
#pragma unroll
        for (int mt = 0; mt < 2; ++mt)
          sc[ntl][mt] = __builtin_amdgcn_mfma_f32_16x16x32_f16(kf, qf[mt][kcq], sc[ntl][mt], 0, 0, 0);
      }
    __builtin_amdgcn_s_setprio(0);

    f16x8 pa[2];
#pragma unroll
    for (int mt = 0; mt < 2; ++mt) {
      const f32x4 s0 = sc[0][mt], s1 = sc[1][mt];
      union { f16x8 v8; f16x2 hh[4]; } u;
      u.hh[0] = __builtin_bit_cast(f16x2, __builtin_amdgcn_cvt_pkrtz(
          __builtin_amdgcn_exp2f(s0[0]), __builtin_amdgcn_exp2f(s0[1])));
      u.hh[1] = __builtin_bit_cast(f16x2, __builtin_amdgcn_cvt_pkrtz(
          __builtin_amdgcn_exp2f(s0[2]), __builtin_amdgcn_exp2f(s0[3])));
      u.hh[2] = __builtin_bit_cast(f16x2, __builtin_amdgcn_cvt_pkrtz(
          __builtin_amdgcn_exp2f(s1[0]), __builtin_amdgcn_exp2f(s1[1])));
      u.hh[3] = __builtin_bit_cast(f16x2, __builtin_amdgcn_cvt_pkrtz(
          __builtin_amdgcn_exp2f(s1[2]), __builtin_amdgcn_exp2f(s1[3])));
      pa[mt] = u.v8;
    }

    __builtin_amdgcn_s_setprio(1);
#pragma unroll
    for (int nt = 0; nt < 4; ++nt) {
      const f16x8 vbf = *(const f16x8*)&smem[2 + rb][(nt * 16 + l15) * 64 + (((wk * 4 + quad) ^ (l15 & 7)) * 8)];
#pragma unroll
      for (int mt = 0; mt < 2; ++mt)
        O[mt][nt] = __builtin_amdgcn_mfma_f32_16x16x32_f16(pa[mt], vbf, O[mt][nt], 0, 0, 0);
    }
#pragma unroll
    for (int mt = 0; mt < 2; ++mt)
      O[mt][4] = __builtin_amdgcn_mfma_f32_16x16x32_f16(pa[mt], vb4, O[mt][4], 0, 0, 0);
    __builtin_amdgcn_s_setprio(0);
  }
#undef ISSUE_TILE

  __syncthreads();
  float* red = (float*)&smem[0][0];
  if (wk) {
    float* dst = red + (size_t)(wq * 64 + lane) * 41;
#pragma unroll
    for (int mt = 0; mt < 2; ++mt)
#pragma unroll
      for (int nt = 0; nt < 5; ++nt)
#pragma unroll
        for (int r = 0; r < 4; ++r) dst[mt * 20 + nt * 4 + r] = O[mt][nt][r];
  }
  __syncthreads();
  if (!wk) {
    const float* src = red + (size_t)(wq * 64 + lane) * 41;
#pragma unroll
    for (int mt = 0; mt < 2; ++mt)
#pragma unroll
      for (int nt = 0; nt < 5; ++nt)
#pragma unroll
        for (int r = 0; r < 4; ++r) O[mt][nt][r] += src[mt * 20 + nt * 4 + r];
#pragma unroll
    for (int mt = 0; mt < 2; ++mt)
#pragma unroll
      for (int r = 0; r < 4; ++r) {
        const float l = __shfl(O[mt][4][r], quad << 4, 64);
        const float inv = 1.f / l;
        const int row = q0 + wq * 32 + mt * 16 + quad * 4 + r;
        f16* o = ao + ((size_t)b * S + row) * E + h * D;
#pragma unroll
        for (int nt = 0; nt < 4; ++nt)
          o[nt * 16 + l15] = (f16)(O[mt][nt][r] * inv);
      }
  }
}

// ---------- dense (unchanged): BM=128, BN=64, triple-buffered, counted vmcnt(6).
__global__ __launch_bounds__(256) void dense_mfma(const f16* __restrict__ A,
                                                  const f16* __restrict__ Wd16,
                                                  const float* __restrict__ bd,
                                                  float* __restrict__ out) {
  __shared__ f16 as[3][128 * 64];   // 48 KB
  __shared__ f16 bs[3][64 * 64];    // 24 KB
  const int t = threadIdx.x;
  const int lane = t & 63;
  const int w = t >> 6;
  const int l15 = lane & 15;
  const int quad = lane >> 4;
  const int m0 = blockIdx.x * 128;
  const int n0 = blockIdx.y * 64;
  const int wm = (w >> 1) * 64, wn = (w & 1) * 32;

  const int srow = (lane >> 3);
  const int schunk = (lane & 7) ^ srow;
  const f16* ga0 = A    + (size_t)(m0 + w * 32 + srow) * E + schunk * 8;
  const f16* gb0 = Wd16 + (size_t)(n0 + w * 16 + srow) * E + schunk * 8;

  constexpr int NT = E / 64;

#define ISSUE_D(tt, ib)                                                        \
  {                                                                            \
    _Pragma("unroll")                                                          \
    for (int i = 0; i < 4; ++i)                                                \
      GLOBAL_LOAD_LDS16(ga0 + (size_t)(i * 8) * E + (tt) * 64,                 \
                        &as[ib][(w * 32 + i * 8) * 64]);                       \
    _Pragma("unroll")                                                          \
    for (int i = 0; i < 2; ++i)                                                \
      GLOBAL_LOAD_LDS16(gb0 + (size_t)(i * 8) * E + (tt) * 64,                 \
                        &bs[ib][(w * 16 + i * 8) * 64]);                       \
  }

  f32x4 acc[4][2];
#pragma unroll
  for (int mt = 0; mt < 4; ++mt)
#pragma unroll
    for (int nt = 0; nt < 2; ++nt) acc[mt][nt] = (f32x4){0.f, 0.f, 0.f, 0.f};

  ISSUE_D(0, 0);
  ISSUE_D(1, 1);
  __asm__ volatile("s_waitcnt vmcnt(6)" ::: "memory");
  __builtin_amdgcn_s_barrier();
  __asm__ volatile("" ::: "memory");

  int rb = 0, ib = 2;
  for (int kt = 0; kt < NT; ++kt) {
    {
      const int tt = (kt + 2 < NT) ? (kt + 2) : (NT - 1);
      ISSUE_D(tt, ib);
    }
    f16x8 af[4][2];
#pragma unroll
    for (int mt = 0; mt < 4; ++mt)
#pragma unroll
      for (int kc = 0; kc < 2; ++kc)
        af[mt][kc] = *(const f16x8*)&as[rb][(wm + mt * 16 + l15) * 64 + (((kc * 4 + quad) ^ (l15 & 7)) * 8)];
#pragma unroll
    for (int kc = 0; kc < 2; ++kc)
#pragma unroll
      for (int nt = 0; nt < 2; ++nt) {
        const f16x8 bf = *(const f16x8*)&bs[rb][(wn + nt * 16 + l15) * 64 + (((kc * 4 + quad) ^ (l15 & 7)) * 8)];
#pragma unroll
        for (int mt = 0; mt < 4; ++mt)
          acc[mt][nt] = __builtin_amdgcn_mfma_f32_16x16x32_f16(af[mt][kc], bf, acc[mt][nt], 0, 0, 0);
      }
    __asm__ volatile("s_waitcnt vmcnt(6)" ::: "memory");
    __builtin_amdgcn_s_barrier();
    __asm__ volatile("" ::: "memory");
    rb = (rb + 1 >= 3) ? 0 : rb + 1;
    ib = (ib + 1 >= 3) ? 0 : ib + 1;
  }
#undef ISSUE_D

#pragma unroll
  for (int nt = 0; nt < 2; ++nt) {
    const int col = n0 + wn + nt * 16 + l15;
    const float bdv = bd[col];
#pragma unroll
    for (int mt = 0; mt < 4; ++mt)
#pragma unroll
      for (int r = 0; r < 4; ++r)
        out[(size_t)(m0 + wm + mt * 16 + quad * 4 + r) * E + col] = acc[mt][nt][r] + bdv;
  }
}

extern "C" void kernel_launch(void* const* d_in, const int* in_sizes, int n_in,
                              void* d_out, int out_size, void* d_ws, size_t ws_size,
                              hipStream_t stream) {
  const float* queries = (const float*)d_in[0];
  const float* values  = (const float*)d_in[1];
  const float* Wv = (const float*)d_in[3];
  const float* bv = (const float*)d_in[4];
  const float* Wk = (const float*)d_in[5];
  const float* bk = (const float*)d_in[6];
  const float* Wq = (const float*)d_in[7];
  const float* bq = (const float*)d_in[8];
  const float* Wd = (const float*)d_in[9];
  const float* bd = (const float*)d_in[10];
  float* out = (float*)d_out;

  char* ws = (char*)d_ws;
  f16* qp    = (f16*)(ws);                          // 8 MB [B,S,H,D]  (natural layout)
  f16* kp    = (f16*)(ws + 8u * 1024 * 1024);       // 8 MB [B,H,S,D]
  f16* vtp   = (f16*)(ws + 16u * 1024 * 1024);      // 8 MB [B,H,D,S] permuted V^T
  f16* ao    = (f16*)(ws + 24u * 1024 * 1024);      // 8 MB [B,S,E]
  f16* wd16  = (f16*)(ws + 32u * 1024 * 1024);      // 2 MB
  float* wkv = (float*)(ws + 34u * 1024 * 1024);    // 16 KB
  float* bkv = (float*)(ws + 34u * 1024 * 1024 + 16384);
  (void)ws_size; (void)in_sizes; (void)n_in; (void)out_size;

  prep<<<16, 256, 0, stream>>>(Wk, Wv, bv, bk, wkv, bkv);
  proj_all<<<2560, 256, 0, stream>>>(queries, values, Wq, bq, wkv, bkv, Wv, bv, Wd,
                                     qp, kp, vtp, wd16);
  attn_mfma<<<dim3(B * H, S / 64), 256, 0, stream>>>(qp, kp, vtp, ao);
  dense_mfma<<<dim3(B * S / 128, E / 64), 256, 0, stream>>>(ao, wd16, bd, out);
}

// Round 13
// 175.463 us; speedup vs baseline: 1.0218x; 1.0218x over previous
//
#include <hip/hip_runtime.h>
#include <hip/hip_bf16.h>
#include <hip/hip_fp16.h>
#include <math.h>

typedef _Float16 f16;
typedef _Float16 f16x8 __attribute__((ext_vector_type(8)));
typedef _Float16 f16x4 __attribute__((ext_vector_type(4)));
typedef _Float16 f16x2 __attribute__((ext_vector_type(2)));
typedef unsigned short u16x8v __attribute__((ext_vector_type(8)));
typedef float f32x4 __attribute__((ext_vector_type(4)));

namespace {
constexpr int B = 2;
constexpr int H = 16;
constexpr int S = 2048;
constexpr int D = 64;
constexpr int E = 1024;
// fold 1/sqrt(64) * log2(e) into Q so softmax uses exp2 directly
constexpr float QSCALE = 0.125f * 1.4426950408889634f;
}

#define GLOBAL_LOAD_LDS16(gp, lp)                                              \
  __builtin_amdgcn_global_load_lds(                                            \
      (const __attribute__((address_space(1))) void*)(gp),                     \
      (__attribute__((address_space(3))) void*)(lp), 16, 0, 0)

// ---------- prep: [blocks 0..1023] Wd fp32->f16 ; [blocks 1024..1039] Wkv = Wk*Wv, bkv = Wk*bv + bk
__global__ __launch_bounds__(256) void prep(const float* __restrict__ Wd, f16* __restrict__ wd16,
                                            const float* __restrict__ Wk, const float* __restrict__ Wv,
                                            const float* __restrict__ bv, const float* __restrict__ bk,
                                            float* __restrict__ Wkv, float* __restrict__ bkv) {
  if (blockIdx.x < 1024) {
    const int i = blockIdx.x * 256 + threadIdx.x;
    const float4 f = ((const float4*)Wd)[i];
    f16x4 o;
    o.x = (f16)f.x; o.y = (f16)f.y; o.z = (f16)f.z; o.w = (f16)f.w;
    *(f16x4*)(wd16 + 4 * (size_t)i) = o;
  } else {
    const int g = (blockIdx.x - 1024) * 256 + threadIdx.x;   // 0..4095
    const int i = g >> 6, j = g & 63;
    float s = 0.f;
#pragma unroll 16
    for (int d = 0; d < 64; ++d) s = fmaf(Wk[i * 64 + d], Wv[d * 64 + j], s);
    Wkv[g] = s;
    if (g < 64) {
      float bb = bk[g];
#pragma unroll 16
      for (int d = 0; d < 64; ++d) bb = fmaf(Wk[g * 64 + d], bv[d], bb);
      bkv[g] = bb;
    }
  }
}

// ---------- projections (R8 structure, fastest measured): blockIdx.y==0 -> Q; ==1 -> V then K
// (x loaded once, two weight passes). Q: natural [b][s][h][d]. K: [b][h][s][d] via LDS bounce.
// V: transposed+permuted vtp[b][h][d][S] (kv(p) = (p>>5)*32 + ((p&7)>>2)*16 + ((p>>3)&3)*4 + (p&3)).
__global__ __launch_bounds__(256) void proj3_mfma(const float* __restrict__ xq,
                                                  const float* __restrict__ xv,
                                                  const float* __restrict__ Wq,
                                                  const float* __restrict__ bq,
                                                  const float* __restrict__ Wv,
                                                  const float* __restrict__ bv,
                                                  const float* __restrict__ Wkv,
                                                  const float* __restrict__ bkv,
                                                  f16* __restrict__ qp,
                                                  f16* __restrict__ vtp,
                                                  f16* __restrict__ kp) {
  __shared__ f16 tb[16 * 16 * 68];   // 34.8 KB bounce (V: [pi][16]; K: [h*16+sl][68])
  const int which = blockIdx.y;
  const float* x = which ? xv : xq;

  const int t = threadIdx.x, lane = t & 63, w = t >> 6;
  const int l15 = lane & 15, quad = lane >> 4;
  const int m0 = (blockIdx.x * 4 + w) * 64;

  f16x8 af[4][2];
#pragma unroll
  for (int mt = 0; mt < 4; ++mt)
#pragma unroll
    for (int kc = 0; kc < 2; ++kc) {
      const float* g = x + (size_t)(m0 + mt * 16 + l15) * 64 + kc * 32 + quad * 8;
      const float4 a = *(const float4*)g, b2 = *(const float4*)(g + 4);
      f16x8 v;
      v[0]=(f16)a.x; v[1]=(f16)a.y; v[2]=(f16)a.z; v[3]=(f16)a.w;
      v[4]=(f16)b2.x; v[5]=(f16)b2.y; v[6]=(f16)b2.z; v[7]=(f16)b2.w;
      af[mt][kc] = v;
    }

  const int npass = which ? 2 : 1;
  for (int pass = 0; pass < npass; ++pass) {
    const float* W    = which ? (pass ? Wkv : Wv) : Wq;
    const float* bias = which ? (pass ? bkv : bv) : bq;
    const bool vpass  = (which == 1) && (pass == 0);
    const bool kpass  = (which == 1) && (pass == 1);
    const float scale = which ? 1.0f : QSCALE;

    f16x8 wf[4][2];
#pragma unroll
    for (int nt = 0; nt < 4; ++nt)
#pragma unroll
      for (int kc = 0; kc < 2; ++kc) {
        const float* g = W + (size_t)(nt * 16 + l15) * 64 + kc * 32 + quad * 8;
        const float4 a = *(const float4*)g, b2 = *(const float4*)(g + 4);
        f16x8 v;
        v[0]=(f16)a.x; v[1]=(f16)a.y; v[2]=(f16)a.z; v[3]=(f16)a.w;
        v[4]=(f16)b2.x; v[5]=(f16)b2.y; v[6]=(f16)b2.z; v[7]=(f16)b2.w;
        wf[nt][kc] = v;
      }

    f32x4 acc[4][4];   // [nt][mt]: rows m = mt*16+l15, cols n = nt*16+quad*4+r
#pragma unroll
    for (int nt = 0; nt < 4; ++nt)
#pragma unroll
      for (int mt = 0; mt < 4; ++mt) acc[nt][mt] = (f32x4){0.f, 0.f, 0.f, 0.f};
#pragma unroll
    for (int kc = 0; kc < 2; ++kc)
#pragma unroll
      for (int nt = 0; nt < 4; ++nt)
#pragma unroll
        for (int mt = 0; mt < 4; ++mt)
          acc[nt][mt] = __builtin_amdgcn_mfma_f32_16x16x32_f16(wf[nt][kc], af[mt][kc], acc[nt][mt], 0, 0, 0);

    float4 bl4[4];
#pragma unroll
    for (int nt = 0; nt < 4; ++nt) bl4[nt] = *(const float4*)&bias[nt * 16 + quad * 4];

#pragma unroll
    for (int mt = 0; mt < 4; ++mt) {
      const int g = m0 + mt * 16 + l15;   // (b*S+s)*H + h
#pragma unroll
      for (int nt = 0; nt < 4; ++nt) {
        const float p0 = (acc[nt][mt][0] + bl4[nt].x) * scale;
        const float p1 = (acc[nt][mt][1] + bl4[nt].y) * scale;
        const float p2 = (acc[nt][mt][2] + bl4[nt].z) * scale;
        const float p3 = (acc[nt][mt][3] + bl4[nt].w) * scale;
        union { f16x4 v4; f16x2 hh[2]; } u;
        u.hh[0] = __builtin_bit_cast(f16x2, __builtin_amdgcn_cvt_pkrtz(p0, p1));
        u.hh[1] = __builtin_bit_cast(f16x2, __builtin_amdgcn_cvt_pkrtz(p2, p3));
        if (vpass) {
          // tb[pi][sl]: pi = h*64 + d, h=l15, d=nt*16+quad*4+r, sl=w*4+mt
#pragma unroll
          for (int r = 0; r < 4; ++r)
            tb[(l15 * 64 + nt * 16 + quad * 4 + r) * 16 + w * 4 + mt] = u.v4[r];
        } else if (kpass) {
          // tb[h*16+sl][68]: coalesced-store bounce
          *(f16x4*)&tb[(l15 * 16 + w * 4 + mt) * 68 + nt * 16 + quad * 4] = u.v4;
        } else {
          // Q: natural layout [b][s][h][d] = row g -> coalesced
          *(f16x4*)(qp + (size_t)g * 64 + nt * 16 + quad * 4) = u.v4;
        }
      }
    }

    if (vpass) {
      __syncthreads();
      const int bsb = blockIdx.x * 16;
      const int bb = bsb >> 11;
      const int sb = bsb & 2047;
      const int off = sb & 63;                              // in {0,16,32,48}
      const int poff = (off & 32) | ((off & 16) >> 2);      // perm-inverse of the off bits
      const int col0 = (sb - off) + poff;
#pragma unroll
      for (int k2 = 0; k2 < 4; ++k2) {
        const int pi = t * 4 + k2;                          // (h,d) pair
        const int h = pi >> 6, d = pi & 63;
        const f16x8 lo = *(const f16x8*)&tb[pi * 16];
        const f16x8 hi = *(const f16x8*)&tb[pi * 16 + 8];
        f16* orow = vtp + ((size_t)(bb * H + h) * 64 + d) * S + col0;
        f16x4 g0, g1, g2, g3;
#pragma unroll
        for (int j = 0; j < 4; ++j) { g0[j]=lo[j]; g1[j]=lo[4+j]; g2[j]=hi[j]; g3[j]=hi[4+j]; }
        *(f16x4*)(orow + 0)  = g0;
        *(f16x4*)(orow + 8)  = g1;
        *(f16x4*)(orow + 16) = g2;
        *(f16x4*)(orow + 24) = g3;
      }
      __syncthreads();
    } else if (kpass) {
      __syncthreads();
      const int bsb = blockIdx.x * 16;
      const int bb = bsb >> 11;
      const int sblk = bsb & 2047;
      const int h = t >> 4, sl = t & 15;
      f16* dst = kp + ((size_t)(bb * H + h) * S + sblk + sl) * 64;
      const f16* src = &tb[t * 68];
#pragma unroll
      for (int c = 0; c < 8; ++c)
        *(f16x8*)(dst + c * 8) = *(const f16x8*)(src + c * 8);
    }
  }
}

// ---------- MFMA flash attention v11: QBLK=128 (512 threads, 8 waves as 4q x 2kv).
// Same per-wave math as v10; each staged 64-kv K/V tile now serves 128 q rows ->
// gload_lds issues, staging VALU, and barriers per unit work all halve (1 load/thread).
// Depth-2 LDS (32 KB), grid (32,16)=512 -> 2 blocks/CU = 4 waves/SIMD.
// In-register P (swapped QK^T + V perm), XOR chunk swizzle, two-stage LDS O-reduce.
__global__ __launch_bounds__(512, 4) void attn_mfma(const f16* __restrict__ qp,
                                                    const f16* __restrict__ kp,
                                                    const f16* __restrict__ vtp,
                                                    f16* __restrict__ ao) {
  __shared__ f16 smem[4][64 * 64];   // [0,1]=K dbuf, [2,3]=V dbuf; f32 scratch at epilogue
  const int t = threadIdx.x, lane = t & 63, w = t >> 6;   // w in 0..7
  const int l15 = lane & 15, quad = lane >> 4;
  const int wq = w >> 1, wk = w & 1;                      // wq 0..3, wk 0..1
  const int bh = blockIdx.x;
  const int b = bh >> 4, h = bh & 15;
  const int q0 = blockIdx.y * 128;
  const f16* kbase = kp + (size_t)bh * S * D;
  const f16* vtbase = vtp + (size_t)bh * 64 * S;

  // staging geometry: one 16B chunk per thread (512 chunks = one 8 KB tile each for K and V).
  // chunk c = t; row = c>>3 (0..63), glob chunk = (c&7)^(row&7) (pre-swizzled source).
  const int row1 = t >> 3;
  const size_t koff = (size_t)row1 * D + (((t & 7) ^ (row1 & 7)) * 8);
  const size_t voff = (size_t)row1 * S + (((t & 7) ^ (row1 & 7)) * 8);

  // wave (wq,wk): q rows q0 + wq*32 + mt*16 + l15
  f16x8 qf[2][2];
#pragma unroll
  for (int mt = 0; mt < 2; ++mt)
#pragma unroll
    for (int kc = 0; kc < 2; ++kc)
      qf[mt][kc] = *(const f16x8*)(qp +
          ((size_t)(b * S + q0 + wq * 32 + mt * 16 + l15) * H + h) * 64 + kc * 32 + quad * 8);

  f16x8 vb4;
#pragma unroll
  for (int j = 0; j < 8; ++j) vb4[j] = (l15 == 0) ? (f16)1.0f : (f16)0.0f;

  f32x4 O[2][5];
#pragma unroll
  for (int mt = 0; mt < 2; ++mt)
#pragma unroll
    for (int nt = 0; nt < 5; ++nt) O[mt][nt] = (f32x4){0.f, 0.f, 0.f, 0.f};

#define ISSUE_TILE(tt, buf)                                                    \
  {                                                                            \
    const f16* gk = kbase + (size_t)(tt) * (64 * D);                           \
    GLOBAL_LOAD_LDS16(gk + koff, &smem[buf][t * 8]);                           \
    const f16* gv = vtbase + (size_t)(tt) * 64;                                \
    GLOBAL_LOAD_LDS16(gv + voff, &smem[2 + (buf)][t * 8]);                     \
  }

  ISSUE_TILE(0, 0);

  for (int kt = 0; kt < S / 64; ++kt) {
    const int rb = kt & 1;
    __asm__ volatile("s_waitcnt vmcnt(0)" ::: "memory");
    __builtin_amdgcn_s_barrier();
    __asm__ volatile("" ::: "memory");
    if (kt + 1 < S / 64) ISSUE_TILE(kt + 1, rb ^ 1);

    // this wave's kv chunk = wk: QK^T swapped -> C[kv][q], q = l15 lane-local
    f32x4 sc[2][2];   // [ntl][mt]
#pragma unroll
    for (int ntl = 0; ntl < 2; ++ntl)
#pragma unroll
      for (int mt = 0; mt < 2; ++mt) sc[ntl][mt] = (f32x4){0.f, 0.f, 0.f, 0.f};
    __builtin_amdgcn_s_setprio(1);
#pragma unroll
    for (int kcq = 0; kcq < 2; ++kcq)
#pragma unroll
      for (int ntl = 0; ntl < 2; ++ntl) {
        const f16x8 kf = *(const f16x8*)&smem[rb][(wk * 32 + ntl * 16 + l15) * 64 + (((kcq * 4 + quad) ^ (l15 & 7)) * 8)];
#pragma unroll
        for (int mt = 0; mt < 2; ++mt)
          sc[ntl][mt] = __builtin_amdgcn_mfma_f32_16x16x32_f16(kf, qf[mt][kcq], sc[ntl][mt], 0, 0, 0);
      }
    __builtin_amdgcn_s_setprio(0);

    // P = exp2(sc) packed into PV A-frags (in-register)
    f16x8 pa[2];
#pragma unroll
    for (int mt = 0; mt < 2; ++mt) {
      const f32x4 s0 = sc[0][mt], s1 = sc[1][mt];
      union { f16x8 v8; f16x2 hh[4]; } u;
      u.hh[0] = __builtin_bit_cast(f16x2, __builtin_amdgcn_cvt_pkrtz(
          __builtin_amdgcn_exp2f(s0[0]), __builtin_amdgcn_exp2f(s0[1])));
      u.hh[1] = __builtin_bit_cast(f16x2, __builtin_amdgcn_cvt_pkrtz(
          __builtin_amdgcn_exp2f(s0[2]), __builtin_amdgcn_exp2f(s0[3])));
      u.hh[2] = __builtin_bit_cast(f16x2, __builtin_amdgcn_cvt_pkrtz(
          __builtin_amdgcn_exp2f(s1[0]), __builtin_amdgcn_exp2f(s1[1])));
      u.hh[3] = __builtin_bit_cast(f16x2, __builtin_amdgcn_cvt_pkrtz(
          __builtin_amdgcn_exp2f(s1[2]), __builtin_amdgcn_exp2f(s1[3])));
      pa[mt] = u.v8;
    }

    // PV += P * V for this wave's kv half; l accumulates in O[mt][4] col 0
    __builtin_amdgcn_s_setprio(1);
#pragma unroll
    for (int nt = 0; nt < 4; ++nt) {
      const f16x8 vbf = *(const f16x8*)&smem[2 + rb][(nt * 16 + l15) * 64 + (((wk * 4 + quad) ^ (l15 & 7)) * 8)];
#pragma unroll
      for (int mt = 0; mt < 2; ++mt)
        O[mt][nt] = __builtin_amdgcn_mfma_f32_16x16x32_f16(pa[mt], vbf, O[mt][nt], 0, 0, 0);
    }
#pragma unroll
    for (int mt = 0; mt < 2; ++mt)
      O[mt][4] = __builtin_amdgcn_mfma_f32_16x16x32_f16(pa[mt], vb4, O[mt][4], 0, 0, 0);
    __builtin_amdgcn_s_setprio(0);
  }
#undef ISSUE_TILE

  // two-stage cross-wave reduce (20 KB scratch per stage): wk=1 -> LDS -> wk=0 adds.
  float* red = (float*)&smem[0][0];
  __syncthreads();
  if (wk) {   // stage A: O[0]
    float* dst = red + (size_t)(wq * 64 + lane) * 20;
#pragma unroll
    for (int nt = 0; nt < 5; ++nt)
#pragma unroll
      for (int r = 0; r < 4; ++r) dst[nt * 4 + r] = O[0][nt][r];
  }
  __syncthreads();
  if (!wk) {
    const float* src = red + (size_t)(wq * 64 + lane) * 20;
#pragma unroll
    for (int nt = 0; nt < 5; ++nt)
#pragma unroll
      for (int r = 0; r < 4; ++r) O[0][nt][r] += src[nt * 4 + r];
  }
  __syncthreads();
  if (wk) {   // stage B: O[1]
    float* dst = red + (size_t)(wq * 64 + lane) * 20;
#pragma unroll
    for (int nt = 0; nt < 5; ++nt)
#pragma unroll
      for (int r = 0; r < 4; ++r) dst[nt * 4 + r] = O[1][nt][r];
  }
  __syncthreads();
  if (!wk) {
    const float* src = red + (size_t)(wq * 64 + lane) * 20;
#pragma unroll
    for (int nt = 0; nt < 5; ++nt)
#pragma unroll
      for (int r = 0; r < 4; ++r) O[1][nt][r] += src[nt * 4 + r];

#pragma unroll
    for (int mt = 0; mt < 2; ++mt)
#pragma unroll
      for (int r = 0; r < 4; ++r) {
        const float l = __shfl(O[mt][4][r], quad << 4, 64);
        const float inv = 1.f / l;
        const int row = q0 + wq * 32 + mt * 16 + quad * 4 + r;
        f16* o = ao + ((size_t)b * S + row) * E + h * D;
#pragma unroll
        for (int nt = 0; nt < 4; ++nt)
          o[nt * 16 + l15] = (f16)(O[mt][nt][r] * inv);
      }
  }
}

// ---------- dense (unchanged): BM=128, BN=64, triple-buffered, counted vmcnt(6).
__global__ __launch_bounds__(256) void dense_mfma(const f16* __restrict__ A,
                                                  const f16* __restrict__ Wd16,
                                                  const float* __restrict__ bd,
                                                  float* __restrict__ out) {
  __shared__ f16 as[3][128 * 64];   // 48 KB
  __shared__ f16 bs[3][64 * 64];    // 24 KB
  const int t = threadIdx.x;
  const int lane = t & 63;
  const int w = t >> 6;
  const int l15 = lane & 15;
  const int quad = lane >> 4;
  const int m0 = blockIdx.x * 128;
  const int n0 = blockIdx.y * 64;
  const int wm = (w >> 1) * 64, wn = (w & 1) * 32;

  const int srow = (lane >> 3);
  const int schunk = (lane & 7) ^ srow;
  const f16* ga0 = A    + (size_t)(m0 + w * 32 + srow) * E + schunk * 8;
  const f16* gb0 = Wd16 + (size_t)(n0 + w * 16 + srow) * E + schunk * 8;

  constexpr int NT = E / 64;

#define ISSUE_D(tt, ib)                                                        \
  {                                                                            \
    _Pragma("unroll")                                                          \
    for (int i = 0; i < 4; ++i)                                                \
      GLOBAL_LOAD_LDS16(ga0 + (size_t)(i * 8) * E + (tt) * 64,                 \
                        &as[ib][(w * 32 + i * 8) * 64]);                       \
    _Pragma("unroll")                                                          \
    for (int i = 0; i < 2; ++i)                                                \
      GLOBAL_LOAD_LDS16(gb0 + (size_t)(i * 8) * E + (tt) * 64,                 \
                        &bs[ib][(w * 16 + i * 8) * 64]);                       \
  }

  f32x4 acc[4][2];
#pragma unroll
  for (int mt = 0; mt < 4; ++mt)
#pragma unroll
    for (int nt = 0; nt < 2; ++nt) acc[mt][nt] = (f32x4){0.f, 0.f, 0.f, 0.f};

  ISSUE_D(0, 0);
  ISSUE_D(1, 1);
  __asm__ volatile("s_waitcnt vmcnt(6)" ::: "memory");
  __builtin_amdgcn_s_barrier();
  __asm__ volatile("" ::: "memory");

  int rb = 0, ib = 2;
  for (int kt = 0; kt < NT; ++kt) {
    {
      const int tt = (kt + 2 < NT) ? (kt + 2) : (NT - 1);
      ISSUE_D(tt, ib);
    }
    f16x8 af[4][2];
#pragma unroll
    for (int mt = 0; mt < 4; ++mt)
#pragma unroll
      for (int kc = 0; kc < 2; ++kc)
        af[mt][kc] = *(const f16x8*)&as[rb][(wm + mt * 16 + l15) * 64 + (((kc * 4 + quad) ^ (l15 & 7)) * 8)];
#pragma unroll
    for (int kc = 0; kc < 2; ++kc)
#pragma unroll
      for (int nt = 0; nt < 2; ++nt) {
        const f16x8 bf = *(const f16x8*)&bs[rb][(wn + nt * 16 + l15) * 64 + (((kc * 4 + quad) ^ (l15 & 7)) * 8)];
#pragma unroll
        for (int mt = 0; mt < 4; ++mt)
          acc[mt][nt] = __builtin_amdgcn_mfma_f32_16x16x32_f16(af[mt][kc], bf, acc[mt][nt], 0, 0, 0);
      }
    __asm__ volatile("s_waitcnt vmcnt(6)" ::: "memory");
    __builtin_amdgcn_s_barrier();
    __asm__ volatile("" ::: "memory");
    rb = (rb + 1 >= 3) ? 0 : rb + 1;
    ib = (ib + 1 >= 3) ? 0 : ib + 1;
  }
#undef ISSUE_D

#pragma unroll
  for (int nt = 0; nt < 2; ++nt) {
    const int col = n0 + wn + nt * 16 + l15;
    const float bdv = bd[col];
#pragma unroll
    for (int mt = 0; mt < 4; ++mt)
#pragma unroll
      for (int r = 0; r < 4; ++r)
        out[(size_t)(m0 + wm + mt * 16 + quad * 4 + r) * E + col] = acc[mt][nt][r] + bdv;
  }
}

extern "C" void kernel_launch(void* const* d_in, const int* in_sizes, int n_in,
                              void* d_out, int out_size, void* d_ws, size_t ws_size,
                              hipStream_t stream) {
  const float* queries = (const float*)d_in[0];
  const float* values  = (const float*)d_in[1];
  const float* Wv = (const float*)d_in[3];
  const float* bv = (const float*)d_in[4];
  const float* Wk = (const float*)d_in[5];
  const float* bk = (const float*)d_in[6];
  const float* Wq = (const float*)d_in[7];
  const float* bq = (const float*)d_in[8];
  const float* Wd = (const float*)d_in[9];
  const float* bd = (const float*)d_in[10];
  float* out = (float*)d_out;

  char* ws = (char*)d_ws;
  f16* qp    = (f16*)(ws);                          // 8 MB [B,S,H,D]  (natural layout)
  f16* kp    = (f16*)(ws + 8u * 1024 * 1024);       // 8 MB [B,H,S,D]
  f16* vtp   = (f16*)(ws + 16u * 1024 * 1024);      // 8 MB [B,H,D,S] permuted V^T
  f16* ao    = (f16*)(ws + 24u * 1024 * 1024);      // 8 MB [B,S,E]
  f16* wd16  = (f16*)(ws + 32u * 1024 * 1024);      // 2 MB
  float* wkv = (float*)(ws + 34u * 1024 * 1024);    // 16 KB
  float* bkv = (float*)(ws + 34u * 1024 * 1024 + 16384);
  (void)ws_size; (void)in_sizes; (void)n_in; (void)out_size;

  prep<<<1040, 256, 0, stream>>>(Wd, wd16, Wk, Wv, bv, bk, wkv, bkv);
  proj3_mfma<<<dim3(256, 2), 256, 0, stream>>>(queries, values, Wq, bq, Wv, bv, wkv, bkv, qp, vtp, kp);
  attn_mfma<<<dim3(B * H, S / 128), 512, 0, stream>>>(qp, kp, vtp, ao);
  dense_mfma<<<dim3(B * S / 128, E / 64), 256, 0, stream>>>(ao, wd16, bd, out);
}

// Round 16
// 174.266 us; speedup vs baseline: 1.0288x; 1.0069x over previous
//
#include <hip/hip_runtime.h>
#include <hip/hip_bf16.h>
#include <hip/hip_fp16.h>
#include <math.h>

typedef _Float16 f16;
typedef _Float16 f16x8 __attribute__((ext_vector_type(8)));
typedef _Float16 f16x4 __attribute__((ext_vector_type(4)));
typedef _Float16 f16x2 __attribute__((ext_vector_type(2)));
typedef unsigned short u16x8v __attribute__((ext_vector_type(8)));
typedef float f32x4 __attribute__((ext_vector_type(4)));

namespace {
constexpr int B = 2;
constexpr int H = 16;
constexpr int S = 2048;
constexpr int D = 64;
constexpr int E = 1024;
// fold 1/sqrt(64) * log2(e) into Q so softmax uses exp2 directly
constexpr float QSCALE = 0.125f * 1.4426950408889634f;
}

#define GLOBAL_LOAD_LDS16(gp, lp)                                              \
  __builtin_amdgcn_global_load_lds(                                            \
      (const __attribute__((address_space(1))) void*)(gp),                     \
      (__attribute__((address_space(3))) void*)(lp), 16, 0, 0)

// ---------- prep: [blocks 0..1023] Wd fp32->f16 ; [blocks 1024..1039] Wkv = Wk*Wv, bkv = Wk*bv + bk
__global__ __launch_bounds__(256) void prep(const float* __restrict__ Wd, f16* __restrict__ wd16,
                                            const float* __restrict__ Wk, const float* __restrict__ Wv,
                                            const float* __restrict__ bv, const float* __restrict__ bk,
                                            float* __restrict__ Wkv, float* __restrict__ bkv) {
  if (blockIdx.x < 1024) {
    const int i = blockIdx.x * 256 + threadIdx.x;
    const float4 f = ((const float4*)Wd)[i];
    f16x4 o;
    o.x = (f16)f.x; o.y = (f16)f.y; o.z = (f16)f.z; o.w = (f16)f.w;
    *(f16x4*)(wd16 + 4 * (size_t)i) = o;
  } else {
    const int g = (blockIdx.x - 1024) * 256 + threadIdx.x;   // 0..4095
    const int i = g >> 6, j = g & 63;
    float s = 0.f;
#pragma unroll 16
    for (int d = 0; d < 64; ++d) s = fmaf(Wk[i * 64 + d], Wv[d * 64 + j], s);
    Wkv[g] = s;
    if (g < 64) {
      float bb = bk[g];
#pragma unroll 16
      for (int d = 0; d < 64; ++d) bb = fmaf(Wk[g * 64 + d], bv[d], bb);
      bkv[g] = bb;
    }
  }
}

// ---------- projections (R8 structure): blockIdx.y==0 -> Q; ==1 -> V then K
// (x loaded once, two weight passes). Q: natural [b][s][h][d]. K: [b][h][s][d] via LDS bounce.
// V: transposed+permuted vtp[b][h][d][S] (kv(p) = (p>>5)*32 + ((p&7)>>2)*16 + ((p>>3)&3)*4 + (p&3)).
__global__ __launch_bounds__(256) void proj3_mfma(const float* __restrict__ xq,
                                                  const float* __restrict__ xv,
                                                  const float* __restrict__ Wq,
                                                  const float* __restrict__ bq,
                                                  const float* __restrict__ Wv,
                                                  const float* __restrict__ bv,
                                                  const float* __restrict__ Wkv,
                                                  const float* __restrict__ bkv,
                                                  f16* __restrict__ qp,
                                                  f16* __restrict__ vtp,
                                                  f16* __restrict__ kp) {
  __shared__ f16 tb[16 * 16 * 68];   // 34.8 KB bounce (V: [pi][16]; K: [h*16+sl][68])
  const int which = blockIdx.y;
  const float* x = which ? xv : xq;

  const int t = threadIdx.x, lane = t & 63, w = t >> 6;
  const int l15 = lane & 15, quad = lane >> 4;
  const int m0 = (blockIdx.x * 4 + w) * 64;

  f16x8 af[4][2];
#pragma unroll
  for (int mt = 0; mt < 4; ++mt)
#pragma unroll
    for (int kc = 0; kc < 2; ++kc) {
      const float* g = x + (size_t)(m0 + mt * 16 + l15) * 64 + kc * 32 + quad * 8;
      const float4 a = *(const float4*)g, b2 = *(const float4*)(g + 4);
      f16x8 v;
      v[0]=(f16)a.x; v[1]=(f16)a.y; v[2]=(f16)a.z; v[3]=(f16)a.w;
      v[4]=(f16)b2.x; v[5]=(f16)b2.y; v[6]=(f16)b2.z; v[7]=(f16)b2.w;
      af[mt][kc] = v;
    }

  const int npass = which ? 2 : 1;
  for (int pass = 0; pass < npass; ++pass) {
    const float* W    = which ? (pass ? Wkv : Wv) : Wq;
    const float* bias = which ? (pass ? bkv : bv) : bq;
    const bool vpass  = (which == 1) && (pass == 0);
    const bool kpass  = (which == 1) && (pass == 1);
    const float scale = which ? 1.0f : QSCALE;

    f16x8 wf[4][2];
#pragma unroll
    for (int nt = 0; nt < 4; ++nt)
#pragma unroll
      for (int kc = 0; kc < 2; ++kc) {
        const float* g = W + (size_t)(nt * 16 + l15) * 64 + kc * 32 + quad * 8;
        const float4 a = *(const float4*)g, b2 = *(const float4*)(g + 4);
        f16x8 v;
        v[0]=(f16)a.x; v[1]=(f16)a.y; v[2]=(f16)a.z; v[3]=(f16)a.w;
        v[4]=(f16)b2.x; v[5]=(f16)b2.y; v[6]=(f16)b2.z; v[7]=(f16)b2.w;
        wf[nt][kc] = v;
      }

    f32x4 acc[4][4];   // [nt][mt]: rows m = mt*16+l15, cols n = nt*16+quad*4+r
#pragma unroll
    for (int nt = 0; nt < 4; ++nt)
#pragma unroll
      for (int mt = 0; mt < 4; ++mt) acc[nt][mt] = (f32x4){0.f, 0.f, 0.f, 0.f};
#pragma unroll
    for (int kc = 0; kc < 2; ++kc)
#pragma unroll
      for (int nt = 0; nt < 4; ++nt)
#pragma unroll
        for (int mt = 0; mt < 4; ++mt)
          acc[nt][mt] = __builtin_amdgcn_mfma_f32_16x16x32_f16(wf[nt][kc], af[mt][kc], acc[nt][mt], 0, 0, 0);

    float4 bl4[4];
#pragma unroll
    for (int nt = 0; nt < 4; ++nt) bl4[nt] = *(const float4*)&bias[nt * 16 + quad * 4];

#pragma unroll
    for (int mt = 0; mt < 4; ++mt) {
      const int g = m0 + mt * 16 + l15;   // (b*S+s)*H + h
#pragma unroll
      for (int nt = 0; nt < 4; ++nt) {
        const float p0 = (acc[nt][mt][0] + bl4[nt].x) * scale;
        const float p1 = (acc[nt][mt][1] + bl4[nt].y) * scale;
        const float p2 = (acc[nt][mt][2] + bl4[nt].z) * scale;
        const float p3 = (acc[nt][mt][3] + bl4[nt].w) * scale;
        union { f16x4 v4; f16x2 hh[2]; } u;
        u.hh[0] = __builtin_bit_cast(f16x2, __builtin_amdgcn_cvt_pkrtz(p0, p1));
        u.hh[1] = __builtin_bit_cast(f16x2, __builtin_amdgcn_cvt_pkrtz(p2, p3));
        if (vpass) {
#pragma unroll
          for (int r = 0; r < 4; ++r)
            tb[(l15 * 64 + nt * 16 + quad * 4 + r) * 16 + w * 4 + mt] = u.v4[r];
        } else if (kpass) {
          *(f16x4*)&tb[(l15 * 16 + w * 4 + mt) * 68 + nt * 16 + quad * 4] = u.v4;
        } else {
          *(f16x4*)(qp + (size_t)g * 64 + nt * 16 + quad * 4) = u.v4;
        }
      }
    }

    if (vpass) {
      __syncthreads();
      const int bsb = blockIdx.x * 16;
      const int bb = bsb >> 11;
      const int sb = bsb & 2047;
      const int off = sb & 63;                              // in {0,16,32,48}
      const int poff = (off & 32) | ((off & 16) >> 2);      // perm-inverse of the off bits
      const int col0 = (sb - off) + poff;
#pragma unroll
      for (int k2 = 0; k2 < 4; ++k2) {
        const int pi = t * 4 + k2;                          // (h,d) pair
        const int h = pi >> 6, d = pi & 63;
        const f16x8 lo = *(const f16x8*)&tb[pi * 16];
        const f16x8 hi = *(const f16x8*)&tb[pi * 16 + 8];
        f16* orow = vtp + ((size_t)(bb * H + h) * 64 + d) * S + col0;
        f16x4 g0, g1, g2, g3;
#pragma unroll
        for (int j = 0; j < 4; ++j) { g0[j]=lo[j]; g1[j]=lo[4+j]; g2[j]=hi[j]; g3[j]=hi[4+j]; }
        *(f16x4*)(orow + 0)  = g0;
        *(f16x4*)(orow + 8)  = g1;
        *(f16x4*)(orow + 16) = g2;
        *(f16x4*)(orow + 24) = g3;
      }
      __syncthreads();
    } else if (kpass) {
      __syncthreads();
      const int bsb = blockIdx.x * 16;
      const int bb = bsb >> 11;
      const int sblk = bsb & 2047;
      const int h = t >> 4, sl = t & 15;
      f16* dst = kp + ((size_t)(bb * H + h) * S + sblk + sl) * 64;
      const f16* src = &tb[t * 68];
#pragma unroll
      for (int c = 0; c < 8; ++c)
        *(f16x8*)(dst + c * 8) = *(const f16x8*)(src + c * 8);
    }
  }
}

// ---------- MFMA flash attention v13: v12 with the CROSS-WAVE RACE FIXED.
// K-register prefetch of tile kt+1 now sits behind a mid-tile (vmcnt(2) + s_barrier)
// pair: per-wave vmcnt + block barrier => tile kt+1 resident BLOCK-WIDE before any
// wave's kfn ds_read (v12's per-wave vmcnt alone was insufficient — other waves'
// global_load_lds may not have landed). Two barriers/tile (R7: barrier count cheap).
// Ledger: ISSUE(kt+2)'s in-flight loads target buf (kt+2)%3, untouched between the
// two barriers; kfn reads buf (kt+1)%3 (resident), consumed at QK(kt+1), overwritten
// at ISSUE(kt+4) two barriers later; PV reads V[kt%3], protected by the end barrier.
__global__ __launch_bounds__(512, 4) void attn_mfma(const f16* __restrict__ qp,
                                                    const f16* __restrict__ kp,
                                                    const f16* __restrict__ vtp,
                                                    f16* __restrict__ ao) {
  __shared__ f16 smem[6][64 * 64];   // [0..2]=K bufs, [3..5]=V bufs (48 KB); f32 scratch at epilogue
  const int t = threadIdx.x, lane = t & 63, w = t >> 6;   // w in 0..7
  const int l15 = lane & 15, quad = lane >> 4;
  const int wq = w >> 1, wk = w & 1;                      // wq 0..3, wk 0..1
  const int bh = blockIdx.x;
  const int b = bh >> 4, h = bh & 15;
  const int q0 = blockIdx.y * 128;
  const f16* kbase = kp + (size_t)bh * S * D;
  const f16* vtbase = vtp + (size_t)bh * 64 * S;

  // staging geometry: one 16B chunk per thread per tensor.
  const int row1 = t >> 3;
  const size_t koff = (size_t)row1 * D + (((t & 7) ^ (row1 & 7)) * 8);
  const size_t voff = (size_t)row1 * S + (((t & 7) ^ (row1 & 7)) * 8);

  // wave (wq,wk): q rows q0 + wq*32 + mt*16 + l15
  f16x8 qf[2][2];
#pragma unroll
  for (int mt = 0; mt < 2; ++mt)
#pragma unroll
    for (int kc = 0; kc < 2; ++kc)
      qf[mt][kc] = *(const f16x8*)(qp +
          ((size_t)(b * S + q0 + wq * 32 + mt * 16 + l15) * H + h) * 64 + kc * 32 + quad * 8);

  f16x8 vb4;
#pragma unroll
  for (int j = 0; j < 8; ++j) vb4[j] = (l15 == 0) ? (f16)1.0f : (f16)0.0f;

  f32x4 O[2][5];
#pragma unroll
  for (int mt = 0; mt < 2; ++mt)
#pragma unroll
    for (int nt = 0; nt < 5; ++nt) O[mt][nt] = (f32x4){0.f, 0.f, 0.f, 0.f};

  // K-frag read offsets for this wave (kv half = wk): [kcq][ntl]
  int kofs[2][2];
#pragma unroll
  for (int kcq = 0; kcq < 2; ++kcq)
#pragma unroll
    for (int ntl = 0; ntl < 2; ++ntl)
      kofs[kcq][ntl] = (wk * 32 + ntl * 16 + l15) * 64 + (((kcq * 4 + quad) ^ (l15 & 7)) * 8);

#define ISSUE_TILE(tt, buf)                                                    \
  {                                                                            \
    const f16* gk = kbase + (size_t)(tt) * (64 * D);                           \
    GLOBAL_LOAD_LDS16(gk + koff, &smem[buf][t * 8]);                           \
    const f16* gv = vtbase + (size_t)(tt) * 64;                                \
    GLOBAL_LOAD_LDS16(gv + voff, &smem[3 + (buf)][t * 8]);                     \
  }

  f16x8 kfA[2][2], kfB[2][2];
  constexpr int NT = S / 64;

  // prologue: tiles 0,1 in flight; drain tile 0 (tile 1's 2 loads stay); barrier ->
  // tile 0 resident block-wide; read kf(0) -> kfA
  ISSUE_TILE(0, 0);
  ISSUE_TILE(1, 1);
  __asm__ volatile("s_waitcnt vmcnt(2)" ::: "memory");
  __builtin_amdgcn_s_barrier();
  __asm__ volatile("" ::: "memory");
#pragma unroll
  for (int kcq = 0; kcq < 2; ++kcq)
#pragma unroll
    for (int ntl = 0; ntl < 2; ++ntl)
      kfA[kcq][ntl] = *(const f16x8*)&smem[0][kofs[kcq][ntl]];

  auto STEP = [&](int kt, f16x8 (&kfc)[2][2], f16x8 (&kfn)[2][2]) {
    // entry: barrier passed; tile kt resident block-wide; kfc = K-frags(kt) in regs;
    // tile kt+1's loads in flight (2/wave).
    {   // issue tile kt+2 (clamped dummy keeps vmcnt uniform; target buf 2 barriers old)
      const int tt = (kt + 2 < NT) ? (kt + 2) : (NT - 1);
      const int ib = (kt + 2) % 3;
      ISSUE_TILE(tt, ib);
    }

    // QK^T swapped, pure-register: sc[ntl][mt] = mfma(K, Q) -> C[kv][q]
    f32x4 sc[2][2];
#pragma unroll
    for (int ntl = 0; ntl < 2; ++ntl)
#pragma unroll
      for (int mt = 0; mt < 2; ++mt) sc[ntl][mt] = (f32x4){0.f, 0.f, 0.f, 0.f};
    __builtin_amdgcn_s_setprio(1);
#pragma unroll
    for (int kcq = 0; kcq < 2; ++kcq)
#pragma unroll
      for (int ntl = 0; ntl < 2; ++ntl)
#pragma unroll
        for (int mt = 0; mt < 2; ++mt)
          sc[ntl][mt] = __builtin_amdgcn_mfma_f32_16x16x32_f16(kfc[kcq][ntl], qf[mt][kcq], sc[ntl][mt], 0, 0, 0);
    __builtin_amdgcn_s_setprio(0);

    // P = exp2(sc) packed into PV A-frags (in-register)
    f16x8 pa[2];
#pragma unroll
    for (int mt = 0; mt < 2; ++mt) {
      const f32x4 s0 = sc[0][mt], s1 = sc[1][mt];
      union { f16x8 v8; f16x2 hh[4]; } u;
      u.hh[0] = __builtin_bit_cast(f16x2, __builtin_amdgcn_cvt_pkrtz(
          __builtin_amdgcn_exp2f(s0[0]), __builtin_amdgcn_exp2f(s0[1])));
      u.hh[1] = __builtin_bit_cast(f16x2, __builtin_amdgcn_cvt_pkrtz(
          __builtin_amdgcn_exp2f(s0[2]), __builtin_amdgcn_exp2f(s0[3])));
      u.hh[2] = __builtin_bit_cast(f16x2, __builtin_amdgcn_cvt_pkrtz(
          __builtin_amdgcn_exp2f(s1[0]), __builtin_amdgcn_exp2f(s1[1])));
      u.hh[3] = __builtin_bit_cast(f16x2, __builtin_amdgcn_cvt_pkrtz(
          __builtin_amdgcn_exp2f(s1[2]), __builtin_amdgcn_exp2f(s1[3])));
      pa[mt] = u.v8;
    }

    // mid-tile sync: own tile-kt+1 loads drained (kt+2's 2 stay in flight), then
    // BARRIER -> all waves' tile-kt+1 loads landed => kfn read is race-free.
    __asm__ volatile("s_waitcnt vmcnt(2)" ::: "memory");
    __builtin_amdgcn_s_barrier();
    __asm__ volatile("" ::: "memory");
    {
      const f16* kb1 = &smem[(kt + 1) % 3][0];
#pragma unroll
      for (int kcq = 0; kcq < 2; ++kcq)
#pragma unroll
        for (int ntl = 0; ntl < 2; ++ntl)
          kfn[kcq][ntl] = *(const f16x8*)(kb1 + kofs[kcq][ntl]);
    }

    // PV += P * V for this wave's kv half; l accumulates in O[mt][4] col 0
    // (kfn ds_reads overlap PV issue; compiler inserts lgkmcnt before kfn's use at QK(kt+1))
    __builtin_amdgcn_s_setprio(1);
    const f16* vbuf = &smem[3 + (kt % 3)][0];
#pragma unroll
    for (int nt = 0; nt < 4; ++nt) {
      const f16x8 vbf = *(const f16x8*)(vbuf + (nt * 16 + l15) * 64 + (((wk * 4 + quad) ^ (l15 & 7)) * 8));
#pragma unroll
      for (int mt = 0; mt < 2; ++mt)
        O[mt][nt] = __builtin_amdgcn_mfma_f32_16x16x32_f16(pa[mt], vbf, O[mt][nt], 0, 0, 0);
    }
#pragma unroll
    for (int mt = 0; mt < 2; ++mt)
      O[mt][4] = __builtin_amdgcn_mfma_f32_16x16x32_f16(pa[mt], vb4, O[mt][4], 0, 0, 0);
    __builtin_amdgcn_s_setprio(0);

    // tile-end barrier: closes all reads of V[kt%3] (and K[kt%3], last read a step ago)
    // before ISSUE(kt+3) overwrites buf (kt%3) at the top of STEP(kt+1).
    __builtin_amdgcn_s_barrier();
    __asm__ volatile("" ::: "memory");
  };

  for (int kt2 = 0; kt2 < NT; kt2 += 2) {
    STEP(kt2 + 0, kfA, kfB);
    STEP(kt2 + 1, kfB, kfA);
  }
#undef ISSUE_TILE

  // two-stage cross-wave reduce (20 KB scratch per stage): wk=1 -> LDS -> wk=0 adds.
  float* red = (float*)&smem[0][0];
  __syncthreads();
  if (wk) {   // stage A: O[0]
    float* dst = red + (size_t)(wq * 64 + lane) * 20;
#pragma unroll
    for (int nt = 0; nt < 5; ++nt)
#pragma unroll
      for (int r = 0; r < 4; ++r) dst[nt * 4 + r] = O[0][nt][r];
  }
  __syncthreads();
  if (!wk) {
    const float* src = red + (size_t)(wq * 64 + lane) * 20;
#pragma unroll
    for (int nt = 0; nt < 5; ++nt)
#pragma unroll
      for (int r = 0; r < 4; ++r) O[0][nt][r] += src[nt * 4 + r];
  }
  __syncthreads();
  if (wk) {   // stage B: O[1]
    float* dst = red + (size_t)(wq * 64 + lane) * 20;
#pragma unroll
    for (int nt = 0; nt < 5; ++nt)
#pragma unroll
      for (int r = 0; r < 4; ++r) dst[nt * 4 + r] = O[1][nt][r];
  }
  __syncthreads();
  if (!wk) {
    const float* src = red + (size_t)(wq * 64 + lane) * 20;
#pragma unroll
    for (int nt = 0; nt < 5; ++nt)
#pragma unroll
      for (int r = 0; r < 4; ++r) O[1][nt][r] += src[nt * 4 + r];

#pragma unroll
    for (int mt = 0; mt < 2; ++mt)
#pragma unroll
      for (int r = 0; r < 4; ++r) {
        const float l = __shfl(O[mt][4][r], quad << 4, 64);
        const float inv = 1.f / l;
        const int row = q0 + wq * 32 + mt * 16 + quad * 4 + r;
        f16* o = ao + ((size_t)b * S + row) * E + h * D;
#pragma unroll
        for (int nt = 0; nt < 4; ++nt)
          o[nt * 16 + l15] = (f16)(O[mt][nt][r] * inv);
      }
  }
}

// ---------- dense (unchanged): BM=128, BN=64, triple-buffered, counted vmcnt(6).
__global__ __launch_bounds__(256) void dense_mfma(const f16* __restrict__ A,
                                                  const f16* __restrict__ Wd16,
                                                  const float* __restrict__ bd,
                                                  float* __restrict__ out) {
  __shared__ f16 as[3][128 * 64];   // 48 KB
  __shared__ f16 bs[3][64 * 64];    // 24 KB
  const int t = threadIdx.x;
  const int lane = t & 63;
  const int w = t >> 6;
  const int l15 = lane & 15;
  const int quad = lane >> 4;
  const int m0 = blockIdx.x * 128;
  const int n0 = blockIdx.y * 64;
  const int wm = (w >> 1) * 64, wn = (w & 1) * 32;

  const int srow = (lane >> 3);
  const int schunk = (lane & 7) ^ srow;
  const f16* ga0 = A    + (size_t)(m0 + w * 32 + srow) * E + schunk * 8;
  const f16* gb0 = Wd16 + (size_t)(n0 + w * 16 + srow) * E + schunk * 8;

  constexpr int NT = E / 64;

#define ISSUE_D(tt, ib)                                                        \
  {                                                                            \
    _Pragma("unroll")                                                          \
    for (int i = 0; i < 4; ++i)                                                \
      GLOBAL_LOAD_LDS16(ga0 + (size_t)(i * 8) * E + (tt) * 64,                 \
                        &as[ib][(w * 32 + i * 8) * 64]);                       \
    _Pragma("unroll")                                                          \
    for (int i = 0; i < 2; ++i)                                                \
      GLOBAL_LOAD_LDS16(gb0 + (size_t)(i * 8) * E + (tt) * 64,                 \
                        &bs[ib][(w * 16 + i * 8) * 64]);                       \
  }

  f32x4 acc[4][2];
#pragma unroll
  for (int mt = 0; mt < 4; ++mt)
#pragma unroll
    for (int nt = 0; nt < 2; ++nt) acc[mt][nt] = (f32x4){0.f, 0.f, 0.f, 0.f};

  ISSUE_D(0, 0);
  ISSUE_D(1, 1);
  __asm__ volatile("s_waitcnt vmcnt(6)" ::: "memory");
  __builtin_amdgcn_s_barrier();
  __asm__ volatile("" ::: "memory");

  int rb = 0, ib = 2;
  for (int kt = 0; kt < NT; ++kt) {
    {
      const int tt = (kt + 2 < NT) ? (kt + 2) : (NT - 1);
      ISSUE_D(tt, ib);
    }
    f16x8 af[4][2];
#pragma unroll
    for (int mt = 0; mt < 4; ++mt)
#pragma unroll
      for (int kc = 0; kc < 2; ++kc)
        af[mt][kc] = *(const f16x8*)&as[rb][(wm + mt * 16 + l15) * 64 + (((kc * 4 + quad) ^ (l15 & 7)) * 8)];
#pragma unroll
    for (int kc = 0; kc < 2; ++kc)
#pragma unroll
      for (int nt = 0; nt < 2; ++nt) {
        const f16x8 bf = *(const f16x8*)&bs[rb][(wn + nt * 16 + l15) * 64 + (((kc * 4 + quad) ^ (l15 & 7)) * 8)];
#pragma unroll
        for (int mt = 0; mt < 4; ++mt)
          acc[mt][nt] = __builtin_amdgcn_mfma_f32_16x16x32_f16(af[mt][kc], bf, acc[mt][nt], 0, 0, 0);
      }
    __asm__ volatile("s_waitcnt vmcnt(6)" ::: "memory");
    __builtin_amdgcn_s_barrier();
    __asm__ volatile("" ::: "memory");
    rb = (rb + 1 >= 3) ? 0 : rb + 1;
    ib = (ib + 1 >= 3) ? 0 : ib + 1;
  }
#undef ISSUE_D

#pragma unroll
  for (int nt = 0; nt < 2; ++nt) {
    const int col = n0 + wn + nt * 16 + l15;
    const float bdv = bd[col];
#pragma unroll
    for (int mt = 0; mt < 4; ++mt)
#pragma unroll
      for (int r = 0; r < 4; ++r)
        out[(size_t)(m0 + wm + mt * 16 + quad * 4 + r) * E + col] = acc[mt][nt][r] + bdv;
  }
}

extern "C" void kernel_launch(void* const* d_in, const int* in_sizes, int n_in,
                              void* d_out, int out_size, void* d_ws, size_t ws_size,
                              hipStream_t stream) {
  const float* queries = (const float*)d_in[0];
  const float* values  = (const float*)d_in[1];
  const float* Wv = (const float*)d_in[3];
  const float* bv = (const float*)d_in[4];
  const float* Wk = (const float*)d_in[5];
  const float* bk = (const float*)d_in[6];
  const float* Wq = (const float*)d_in[7];
  const float* bq = (const float*)d_in[8];
  const float* Wd = (const float*)d_in[9];
  const float* bd = (const float*)d_in[10];
  float* out = (float*)d_out;

  char* ws = (char*)d_ws;
  f16* qp    = (f16*)(ws);                          // 8 MB [B,S,H,D]  (natural layout)
  f16* kp    = (f16*)(ws + 8u * 1024 * 1024);       // 8 MB [B,H,S,D]
  f16* vtp   = (f16*)(ws + 16u * 1024 * 1024);      // 8 MB [B,H,D,S] permuted V^T
  f16* ao    = (f16*)(ws + 24u * 1024 * 1024);      // 8 MB [B,S,E]
  f16* wd16  = (f16*)(ws + 32u * 1024 * 1024);      // 2 MB
  float* wkv = (float*)(ws + 34u * 1024 * 1024);    // 16 KB
  float* bkv = (float*)(ws + 34u * 1024 * 1024 + 16384);
  (void)ws_size; (void)in_sizes; (void)n_in; (void)out_size;

  prep<<<1040, 256, 0, stream>>>(Wd, wd16, Wk, Wv, bv, bk, wkv, bkv);
  proj3_mfma<<<dim3(256, 2), 256, 0, stream>>>(queries, values, Wq, bq, Wv, bv, wkv, bkv, qp, vtp, kp);
  attn_mfma<<<dim3(B * H, S / 128), 512, 0, stream>>>(qp, kp, vtp, ao);
  dense_mfma<<<dim3(B * S / 128, E / 64), 256, 0, stream>>>(ao, wd16, bd, out);
}